// Round 3
// baseline (539.428 us; speedup 1.0000x reference)
//
#include <hip/hip_runtime.h>
#include <hip/hip_bf16.h>
#include <stdint.h>

#define HH 768
#define WW 768
#define NN 200000
#define CI 256
#define CB 64

typedef __attribute__((ext_vector_type(8))) __bf16 bf16x8;
typedef __attribute__((ext_vector_type(4))) float f32x4;
typedef __attribute__((ext_vector_type(4))) unsigned short u16x4;

#define SGB __builtin_amdgcn_sched_group_barrier

__device__ inline unsigned short f2bf(float f) {
    union { float f; unsigned int i; } v; v.f = f;
    unsigned int r = v.i + 0x7FFF + ((v.i >> 16) & 1);
    return (unsigned short)(r >> 16);
}
__device__ inline f32x4 mfma16(bf16x8 a, bf16x8 b, f32x4 c) {
    return __builtin_amdgcn_mfma_f32_16x16x32_bf16(a, b, c, 0, 0, 0);
}
__device__ inline bf16x8 ldfrag(const unsigned short* p) {
    return *(const bf16x8*)p;
}
__device__ inline bf16x8 cvt8(float4 f0, float4 f1) {
    bf16x8 a;
    a[0] = (__bf16)f0.x; a[1] = (__bf16)f0.y; a[2] = (__bf16)f0.z; a[3] = (__bf16)f0.w;
    a[4] = (__bf16)f1.x; a[5] = (__bf16)f1.y; a[6] = (__bf16)f1.z; a[7] = (__bf16)f1.w;
    return a;
}

// ---------------- prep kernels ----------------

__global__ void k_scatter(const int* __restrict__ coords, int* __restrict__ idx_map) {
    int i = blockIdx.x * 256 + threadIdx.x;
    if (i < NN) idx_map[coords[i]] = i;
}

__global__ void k_prepw(const float* __restrict__ w1,
                        const float* __restrict__ w2,
                        const float* __restrict__ w3,
                        unsigned short* __restrict__ w1t,
                        unsigned short* __restrict__ w2t,
                        unsigned short* __restrict__ w3t) {
    int tid = blockIdx.x * 256 + threadIdx.x;
    int stride = gridDim.x * 256;
    for (int i = tid; i < CI * CB; i += stride) {      // w1 [256][64] -> w1t [64][256]
        int k = i / CB, n = i % CB;
        w1t[n * CI + k] = f2bf(w1[i]);
    }
    for (int i = tid; i < 9 * CB * CB; i += stride) {  // w2 [9][64][64] -> per-tap [n][k]
        int t = i / (CB * CB), rem = i % (CB * CB);
        int k = rem / CB, n = rem % CB;
        w2t[t * CB * CB + n * CB + k] = f2bf(w2[i]);
    }
    for (int i = tid; i < CB * CI; i += stride) {      // w3 [64][256] -> w3t [256][64]
        int k = i / CI, n = i % CI;
        w3t[n * CB + k] = f2bf(w3[i]);
    }
}

// ---------------- stage 1: out1 = relu((feats @ w1)*s1 + b1), N x 64 ----------------
// 64 rows/wave, explicit 2-deep K pipeline: batch of 12 loads (8 feats float4 + 4 w1t)
// in flight while 16 MFMAs of the previous K-step run. SGB pins [cvt][loads][MFMA].

__global__ __launch_bounds__(256, 2) void k_gemm1(const float* __restrict__ feats,
                                                  const unsigned short* __restrict__ w1t,
                                                  const float* __restrict__ s1,
                                                  const float* __restrict__ b1,
                                                  unsigned short* __restrict__ out1) {
    const int wave = threadIdx.x >> 6;
    const int lane = threadIdx.x & 63;
    const int m = lane & 15;
    const int quad = lane >> 4;
    const int row0 = blockIdx.x * 256 + wave * 64;
    if (row0 >= NN) return;

    const float* arow[4];
#pragma unroll
    for (int rt = 0; rt < 4; ++rt)
        arow[rt] = feats + (size_t)(row0 + rt * 16 + m) * CI + quad * 8;

    f32x4 acc[4][4];   // [rt][ct]
#pragma unroll
    for (int rt = 0; rt < 4; ++rt)
#pragma unroll
        for (int ct = 0; ct < 4; ++ct) acc[rt][ct] = (f32x4){0.f, 0.f, 0.f, 0.f};

    float4 araw[2][4][2];   // [parity][rt][half]
    bf16x8 bfr[2][4];       // [parity][ct]
#pragma unroll
    for (int rt = 0; rt < 4; ++rt) {
        araw[0][rt][0] = *(const float4*)(arow[rt]);
        araw[0][rt][1] = *(const float4*)(arow[rt] + 4);
    }
#pragma unroll
    for (int ct = 0; ct < 4; ++ct)
        bfr[0][ct] = ldfrag(w1t + (ct * 16 + m) * CI + quad * 8);

#pragma unroll
    for (int ks = 0; ks < 8; ++ks) {
        const int cur = ks & 1, nxt = cur ^ 1;
        bf16x8 af[4];
#pragma unroll
        for (int rt = 0; rt < 4; ++rt)
            af[rt] = cvt8(araw[cur][rt][0], araw[cur][rt][1]);
        if (ks < 7) {
#pragma unroll
            for (int rt = 0; rt < 4; ++rt) {
                araw[nxt][rt][0] = *(const float4*)(arow[rt] + (ks + 1) * 32);
                araw[nxt][rt][1] = *(const float4*)(arow[rt] + (ks + 1) * 32 + 4);
            }
#pragma unroll
            for (int ct = 0; ct < 4; ++ct)
                bfr[nxt][ct] = ldfrag(w1t + (ct * 16 + m) * CI + quad * 8 + (ks + 1) * 32);
        }
#pragma unroll
        for (int ct = 0; ct < 4; ++ct)
#pragma unroll
            for (int rt = 0; rt < 4; ++rt)
                acc[rt][ct] = mfma16(bfr[cur][ct], af[rt], acc[rt][ct]);
        SGB(0x2, 16, 0);    // cvt VALU (forces wait on cur batch)
        SGB(0x20, 12, 0);   // next-step loads in flight
        SGB(0x8, 16, 0);    // cur MFMAs
    }

#pragma unroll
    for (int rt = 0; rt < 4; ++rt)
#pragma unroll
        for (int ct = 0; ct < 4; ++ct) {
            int row = row0 + rt * 16 + m;
            int c0 = ct * 16 + quad * 4;
            float4 sc = *(const float4*)(s1 + c0);
            float4 bi = *(const float4*)(b1 + c0);
            float v0 = acc[rt][ct][0] * sc.x + bi.x;
            float v1 = acc[rt][ct][1] * sc.y + bi.y;
            float v2 = acc[rt][ct][2] * sc.z + bi.z;
            float v3 = acc[rt][ct][3] * sc.w + bi.w;
            u16x4 o;
            o.x = f2bf(v0 > 0.f ? v0 : 0.f);
            o.y = f2bf(v1 > 0.f ? v1 : 0.f);
            o.z = f2bf(v2 > 0.f ? v2 : 0.f);
            o.w = f2bf(v3 > 0.f ? v3 : 0.f);
            *(u16x4*)(out1 + (size_t)row * CB + c0) = o;
        }
}

// ---------------- fused stage 2+3 ----------------
// 64 rows/wave. Conv taps run a 2-deep pipeline: 16 loads (8 gathers + 8 w2t) of tap
// t+1 in flight under the 32 MFMAs of tap t. Conv acc is re-laid out via wave-local
// LDS transpose, then 4 output chunks of gemm3 with residual loads issued early
// (consumed only in the epilogue, covered by w3t loads + 32 MFMAs).

__global__ __launch_bounds__(256, 2) void k_conv3(const unsigned short* __restrict__ out1,
                                                  const unsigned short* __restrict__ w2t,
                                                  const unsigned short* __restrict__ w3t,
                                                  const int* __restrict__ coords,
                                                  const int* __restrict__ idx_map,
                                                  const float* __restrict__ s2,
                                                  const float* __restrict__ b2,
                                                  const float* __restrict__ s3,
                                                  const float* __restrict__ b3,
                                                  const unsigned short* __restrict__ zrow,
                                                  const float* __restrict__ feats,
                                                  float* __restrict__ out) {
    __shared__ int s_nbr[256 * 9];
    __shared__ unsigned short s_x[256][68];   // transpose buffer, pad 64->68

    const int tid = threadIdx.x;
    const int wave = tid >> 6;
    const int lane = tid & 63;
    const int m = lane & 15;
    const int quad = lane >> 4;
    const int row0 = blockIdx.x * 256 + wave * 64;
    const bool live = (row0 < NN);

    // ---- neighbor table (256 rows, one per thread) ----
    {
        int grow = blockIdx.x * 256 + tid;
        if (grow < NN) {
            int c = coords[grow];
            int y = c / WW, x = c - y * WW;
#pragma unroll
            for (int t = 0; t < 9; ++t) {
                int dy = t / 3 - 1, dx = t % 3 - 1;
                int ny = y + dy, nx = x + dx;
                int r = -1;
                if (ny >= 0 && ny < HH && nx >= 0 && nx < WW) r = idx_map[ny * WW + nx];
                s_nbr[tid * 9 + t] = r;
            }
        } else {
#pragma unroll
            for (int t = 0; t < 9; ++t) s_nbr[tid * 9 + t] = -1;
        }
    }
    __syncthreads();
    if (!live) return;

    // ---- conv 3x3, 2-deep tap pipeline ----
    f32x4 acc[4][4];   // [rt][ct]
#pragma unroll
    for (int rt = 0; rt < 4; ++rt)
#pragma unroll
        for (int ct = 0; ct < 4; ++ct) acc[rt][ct] = (f32x4){0.f, 0.f, 0.f, 0.f};

    bf16x8 ga[2][4][2];   // [parity][rt][half]
    bf16x8 wb[2][2][4];   // [parity][ks][ct]

#pragma unroll
    for (int rt = 0; rt < 4; ++rt) {
        int r = s_nbr[(wave * 64 + rt * 16 + m) * 9 + 0];
        const unsigned short* base = (r >= 0) ? (out1 + (size_t)r * CB) : zrow;
        ga[0][rt][0] = ldfrag(base + quad * 8);
        ga[0][rt][1] = ldfrag(base + quad * 8 + 32);
    }
#pragma unroll
    for (int ks = 0; ks < 2; ++ks)
#pragma unroll
        for (int ct = 0; ct < 4; ++ct)
            wb[0][ks][ct] = ldfrag(w2t + (ct * 16 + m) * CB + quad * 8 + ks * 32);

#pragma unroll
    for (int t = 0; t < 9; ++t) {
        const int cur = t & 1, nxt = cur ^ 1;
        if (t < 8) {
#pragma unroll
            for (int rt = 0; rt < 4; ++rt) {
                int r = s_nbr[(wave * 64 + rt * 16 + m) * 9 + t + 1];
                const unsigned short* base = (r >= 0) ? (out1 + (size_t)r * CB) : zrow;
                ga[nxt][rt][0] = ldfrag(base + quad * 8);
                ga[nxt][rt][1] = ldfrag(base + quad * 8 + 32);
            }
#pragma unroll
            for (int ks = 0; ks < 2; ++ks)
#pragma unroll
                for (int ct = 0; ct < 4; ++ct)
                    wb[nxt][ks][ct] = ldfrag(w2t + (t + 1) * CB * CB
                                             + (ct * 16 + m) * CB + quad * 8 + ks * 32);
        }
#pragma unroll
        for (int ks = 0; ks < 2; ++ks)
#pragma unroll
            for (int ct = 0; ct < 4; ++ct)
#pragma unroll
                for (int rt = 0; rt < 4; ++rt)
                    acc[rt][ct] = mfma16(wb[cur][ks][ct], ga[cur][rt][ks], acc[rt][ct]);
        SGB(0x100, 4, 0);   // next-tap nbr LDS reads
        SGB(0x20, 16, 0);   // next-tap global loads in flight
        SGB(0x8, 32, 0);    // cur-tap MFMAs
    }

    // ---- bn2 + relu -> bf16 -> wave-local LDS transpose ----
#pragma unroll
    for (int rt = 0; rt < 4; ++rt)
#pragma unroll
        for (int ct = 0; ct < 4; ++ct) {
            int c0 = ct * 16 + quad * 4;
            float4 sc = *(const float4*)(s2 + c0);
            float4 bi = *(const float4*)(b2 + c0);
            float v0 = acc[rt][ct][0] * sc.x + bi.x;
            float v1 = acc[rt][ct][1] * sc.y + bi.y;
            float v2 = acc[rt][ct][2] * sc.z + bi.z;
            float v3 = acc[rt][ct][3] * sc.w + bi.w;
            u16x4 o;
            o.x = f2bf(v0 > 0.f ? v0 : 0.f);
            o.y = f2bf(v1 > 0.f ? v1 : 0.f);
            o.z = f2bf(v2 > 0.f ? v2 : 0.f);
            o.w = f2bf(v3 > 0.f ? v3 : 0.f);
            *(u16x4*)&s_x[wave * 64 + rt * 16 + m][c0] = o;
        }

    bf16x8 a3[4][2];
#pragma unroll
    for (int rt = 0; rt < 4; ++rt)
#pragma unroll
        for (int ks = 0; ks < 2; ++ks)
            a3[rt][ks] = ldfrag(&s_x[wave * 64 + rt * 16 + m][ks * 32 + quad * 8]);

    // ---- gemm3: 4 chunks of 64 cols ----
#pragma unroll
    for (int cc = 0; cc < 4; ++cc) {
        const int cbase = cc * 64;

        // residual loads first: consumed only in the epilogue below
        float4 res[4][4];
#pragma unroll
        for (int rt = 0; rt < 4; ++rt)
#pragma unroll
            for (int ct = 0; ct < 4; ++ct)
                res[rt][ct] = *(const float4*)(feats + (size_t)(row0 + rt * 16 + m) * CI
                                               + cbase + ct * 16 + quad * 4);

        bf16x8 w3f[2][4];
#pragma unroll
        for (int ks = 0; ks < 2; ++ks)
#pragma unroll
            for (int ct = 0; ct < 4; ++ct)
                w3f[ks][ct] = ldfrag(w3t + (cbase + ct * 16 + m) * CB + quad * 8 + ks * 32);

        f32x4 acc3[4][4];
#pragma unroll
        for (int rt = 0; rt < 4; ++rt)
#pragma unroll
            for (int ct = 0; ct < 4; ++ct) acc3[rt][ct] = (f32x4){0.f, 0.f, 0.f, 0.f};

#pragma unroll
        for (int ks = 0; ks < 2; ++ks)
#pragma unroll
            for (int ct = 0; ct < 4; ++ct)
#pragma unroll
                for (int rt = 0; rt < 4; ++rt)
                    acc3[rt][ct] = mfma16(w3f[ks][ct], a3[rt][ks], acc3[rt][ct]);

#pragma unroll
        for (int rt = 0; rt < 4; ++rt)
#pragma unroll
            for (int ct = 0; ct < 4; ++ct) {
                int row = row0 + rt * 16 + m;
                int c0 = cbase + ct * 16 + quad * 4;
                float4 sc = *(const float4*)(s3 + c0);
                float4 bi = *(const float4*)(b3 + c0);
                float4 f = res[rt][ct];
                float4 v;
                v.x = acc3[rt][ct][0] * sc.x + bi.x + f.x;
                v.y = acc3[rt][ct][1] * sc.y + bi.y + f.y;
                v.z = acc3[rt][ct][2] * sc.z + bi.z + f.z;
                v.w = acc3[rt][ct][3] * sc.w + bi.w + f.w;
                v.x = v.x > 0.f ? v.x : 0.f;
                v.y = v.y > 0.f ? v.y : 0.f;
                v.z = v.z > 0.f ? v.z : 0.f;
                v.w = v.w > 0.f ? v.w : 0.f;
                *(float4*)(out + (size_t)row * CI + c0) = v;
            }
        SGB(0x20, 24, 0);   // residual + w3t loads
        SGB(0x8, 32, 0);    // MFMAs
        SGB(0x40, 16, 0);   // stores
    }
}

// ---------------- launch ----------------

extern "C" void kernel_launch(void* const* d_in, const int* in_sizes, int n_in,
                              void* d_out, int out_size, void* d_ws, size_t ws_size,
                              hipStream_t stream) {
    const float* feats = (const float*)d_in[0];
    const int* coords = (const int*)d_in[1];
    const float* w1 = (const float*)d_in[2];
    const float* w2 = (const float*)d_in[3];
    const float* w3 = (const float*)d_in[4];
    const float* s1 = (const float*)d_in[5];
    const float* b1 = (const float*)d_in[6];
    const float* s2 = (const float*)d_in[7];
    const float* b2 = (const float*)d_in[8];
    const float* s3 = (const float*)d_in[9];
    const float* b3 = (const float*)d_in[10];
    float* out = (float*)d_out;

    char* ws = (char*)d_ws;
    int* idx_map        = (int*)(ws + 0);                       // 2,359,296
    unsigned short* w1t = (unsigned short*)(ws + 2359296);      // 32,768
    unsigned short* w2t = (unsigned short*)(ws + 2392064);      // 73,728
    unsigned short* w3t = (unsigned short*)(ws + 2465792);      // 32,768
    unsigned short* out1= (unsigned short*)(ws + 2498560);      // 25,600,000
    unsigned short* zrow= (unsigned short*)(ws + 53698560);     // 128 zero bytes
    // total: 53,698,688 bytes

    hipMemsetAsync(idx_map, 0xFF, (size_t)HH * WW * 4, stream);
    hipMemsetAsync(zrow, 0x00, 128, stream);
    k_scatter<<<(NN + 255) / 256, 256, 0, stream>>>(coords, idx_map);
    k_prepw<<<64, 256, 0, stream>>>(w1, w2, w3, w1t, w2t, w3t);
    k_gemm1<<<(NN + 255) / 256, 256, 0, stream>>>(feats, w1t, s1, b1, out1);
    k_conv3<<<(NN + 255) / 256, 256, 0, stream>>>(out1, w2t, w3t, coords, idx_map,
                                                  s2, b2, s3, b3, zrow, feats, out);
}

// Round 5
// 533.114 us; speedup vs baseline: 1.0118x; 1.0118x over previous
//
#include <hip/hip_runtime.h>
#include <hip/hip_bf16.h>
#include <stdint.h>

#define HH 768
#define WW 768
#define NN 200000
#define CI 256
#define CB 64

typedef __attribute__((ext_vector_type(8))) __bf16 bf16x8;
typedef __attribute__((ext_vector_type(4))) float f32x4;
typedef __attribute__((ext_vector_type(4))) unsigned short u16x4;

__device__ inline unsigned short f2bf(float f) {
    union { float f; unsigned int i; } v; v.f = f;
    unsigned int r = v.i + 0x7FFF + ((v.i >> 16) & 1);
    return (unsigned short)(r >> 16);
}
__device__ inline f32x4 mfma16(bf16x8 a, bf16x8 b, f32x4 c) {
    return __builtin_amdgcn_mfma_f32_16x16x32_bf16(a, b, c, 0, 0, 0);
}
__device__ inline bf16x8 ldfrag(const unsigned short* p) {
    return *(const bf16x8*)p;
}
__device__ inline bf16x8 cvt8(float4 f0, float4 f1) {
    bf16x8 a;
    a[0] = (__bf16)f0.x; a[1] = (__bf16)f0.y; a[2] = (__bf16)f0.z; a[3] = (__bf16)f0.w;
    a[4] = (__bf16)f1.x; a[5] = (__bf16)f1.y; a[6] = (__bf16)f1.z; a[7] = (__bf16)f1.w;
    return a;
}
// async global->LDS DMA, 16B/lane; LDS dest = wave-uniform base + lane*16 (HW rule)
__device__ inline void dma16(const float* g, float* lds_base_uniform) {
    __builtin_amdgcn_global_load_lds(
        (const __attribute__((address_space(1))) unsigned int*)g,
        (__attribute__((address_space(3))) unsigned int*)lds_base_uniform, 16, 0, 0);
}
#define FENCE() __builtin_amdgcn_sched_barrier(0)
#define LGKM0() do { asm volatile("s_waitcnt lgkmcnt(0)" ::: "memory"); FENCE(); } while (0)

// ---------------- prep kernels ----------------

__global__ void k_scatter(const int* __restrict__ coords, int* __restrict__ idx_map) {
    int i = blockIdx.x * 256 + threadIdx.x;
    if (i < NN) idx_map[coords[i]] = i;
}

__global__ void k_prepw(const float* __restrict__ w1,
                        const float* __restrict__ w2,
                        const float* __restrict__ w3,
                        unsigned short* __restrict__ w1t,
                        unsigned short* __restrict__ w2t,
                        unsigned short* __restrict__ w3t) {
    int tid = blockIdx.x * 256 + threadIdx.x;
    int stride = gridDim.x * 256;
    for (int i = tid; i < CI * CB; i += stride) {      // w1 [256][64] -> w1t [64][256]
        int k = i / CB, n = i % CB;
        w1t[n * CI + k] = f2bf(w1[i]);
    }
    for (int i = tid; i < 9 * CB * CB; i += stride) {  // w2 [9][64][64] -> per-tap [n][k]
        int t = i / (CB * CB), rem = i % (CB * CB);
        int k = rem / CB, n = rem % CB;
        w2t[t * CB * CB + n * CB + k] = f2bf(w2[i]);
    }
    for (int i = tid; i < CB * CI; i += stride) {      // w3 [64][256] -> w3t [256][64]
        int k = i / CI, n = i % CI;
        w3t[n * CB + k] = f2bf(w3[i]);
    }
}

// ---------------- stage 1: out1 = relu((feats @ w1)*s1 + b1), N x 64 ----------------
// 128 rows/block, 4 waves x 32 rows. feats staged via global_load_lds in 32-col
// chunks, per-wave-private [32][32] f32 tiles, double-buffered 2 chunks deep.
// No barriers (per-wave-private tiles). XOR swizzle (granule ^ row&7) applied on the
// GLOBAL source (DMA LDS dest must be linear); read undoes it -> 2-way (free) banks.
// Counted vmcnt waits (FIFO semantics): per iter, ops younger than stage(ks) are
// {w1t x4, stage(ks+1) x4} = 8 -> vmcnt(8); first/last iter have only 4 -> vmcnt(4).

__global__ __launch_bounds__(256, 4) void k_gemm1(const float* __restrict__ feats,
                                                  const unsigned short* __restrict__ w1t,
                                                  const float* __restrict__ s1,
                                                  const float* __restrict__ b1,
                                                  unsigned short* __restrict__ out1) {
    __shared__ float sA[4][2][32][32];   // [wave][buf][row][col, granule-swizzled]

    const int wave = threadIdx.x >> 6;
    const int lane = threadIdx.x & 63;
    const int m = lane & 15;
    const int quad = lane >> 4;
    const int row0 = blockIdx.x * 128 + wave * 32;
    if (row0 >= NN) return;

    // DMA instr j writes rows j*8 + (lane>>3); phys granule lane&7 (16B granules).
    // Phys granule g of row r holds logical granule g ^ (r&7):
    const int srow = lane >> 3;                 // row within instr; (row&7) == srow
    const int sc4 = (lane & 7) ^ srow;          // logical granule fetched
    const float* fbase = feats + (size_t)(row0 + srow) * CI + sc4 * 4;

    auto stageA = [&](int ks, int b) {
#pragma unroll
        for (int j = 0; j < 4; ++j)
            dma16(fbase + (size_t)(j * 8) * CI + ks * 32, &sA[wave][b][j * 8][0]);
    };

    f32x4 acc[2][4];   // [rt][ct]
#pragma unroll
    for (int rt = 0; rt < 2; ++rt)
#pragma unroll
        for (int ct = 0; ct < 4; ++ct) acc[rt][ct] = (f32x4){0.f, 0.f, 0.f, 0.f};

    stageA(0, 0);
    stageA(1, 1);

#pragma unroll
    for (int ks = 0; ks < 8; ++ks) {
        const int b = ks & 1;
        // wait for buf b's 4 DMAs (all but the N youngest vmcnt ops are complete)
        if (ks == 0 || ks == 7) {
            asm volatile("s_waitcnt vmcnt(4)" ::: "memory");
        } else {
            asm volatile("s_waitcnt vmcnt(8)" ::: "memory");
        }
        FENCE();

        bf16x8 bfr[4];
#pragma unroll
        for (int ct = 0; ct < 4; ++ct)
            bfr[ct] = ldfrag(w1t + (ct * 16 + m) * CI + quad * 8 + ks * 32);

        bf16x8 af[2];
#pragma unroll
        for (int rt = 0; rt < 2; ++rt) {
            const float* rp = &sA[wave][b][rt * 16 + m][0];
            float4 f0 = *(const float4*)(rp + (((2 * quad + 0) ^ (m & 7)) * 4));
            float4 f1 = *(const float4*)(rp + (((2 * quad + 1) ^ (m & 7)) * 4));
            af[rt] = cvt8(f0, f1);
        }
        // WAR: LDS reads landed in regs before DMA may overwrite buf b
        LGKM0();
        if (ks < 6) stageA(ks + 2, b);

#pragma unroll
        for (int ct = 0; ct < 4; ++ct)
#pragma unroll
            for (int rt = 0; rt < 2; ++rt)
                acc[rt][ct] = mfma16(bfr[ct], af[rt], acc[rt][ct]);
    }

#pragma unroll
    for (int rt = 0; rt < 2; ++rt)
#pragma unroll
        for (int ct = 0; ct < 4; ++ct) {
            int row = row0 + rt * 16 + m;
            int c0 = ct * 16 + quad * 4;
            float4 sc = *(const float4*)(s1 + c0);
            float4 bi = *(const float4*)(b1 + c0);
            float v0 = acc[rt][ct][0] * sc.x + bi.x;
            float v1 = acc[rt][ct][1] * sc.y + bi.y;
            float v2 = acc[rt][ct][2] * sc.z + bi.z;
            float v3 = acc[rt][ct][3] * sc.w + bi.w;
            u16x4 o;
            o.x = f2bf(v0 > 0.f ? v0 : 0.f);
            o.y = f2bf(v1 > 0.f ? v1 : 0.f);
            o.z = f2bf(v2 > 0.f ? v2 : 0.f);
            o.w = f2bf(v3 > 0.f ? v3 : 0.f);
            *(u16x4*)(out1 + (size_t)row * CB + c0) = o;
        }
}

// ---------------- fused stage 2+3 ----------------
// 256 rows/block, 4 waves x 64 rows. Residual feats DMA-staged in 16-col chunks
// ([64][16] f32 per wave), double-buffered; chunks 0,1 issued BEFORE the conv loop
// (no reg cost, lands during conv). Conv keeps the 2-deep register gather pipeline.
// gemm3 phase: 16 chunks of 16 cols; vmcnt(0) at the conv->gemm3 boundary, then
// counted vmcnt(8) per chunk (ops younger than stage(cc): {w3t2+st4+restage4}+{w3t2}
// = 12 steady, 8 at tail -> vmcnt(8) safe everywhere).

__global__ __launch_bounds__(256, 2) void k_conv3(const unsigned short* __restrict__ out1,
                                                  const unsigned short* __restrict__ w2t,
                                                  const unsigned short* __restrict__ w3t,
                                                  const int* __restrict__ coords,
                                                  const int* __restrict__ idx_map,
                                                  const float* __restrict__ s2,
                                                  const float* __restrict__ b2,
                                                  const float* __restrict__ s3,
                                                  const float* __restrict__ b3,
                                                  const unsigned short* __restrict__ zrow,
                                                  const float* __restrict__ feats,
                                                  float* __restrict__ out) {
    __shared__ int s_nbr[256 * 9];                 //  9216 B
    __shared__ unsigned short s_x[4][16][68];      //  8704 B (per-rt transpose)
    __shared__ float s_res[2][4][64][16];          // 32768 B residual dbuf
    // total 50688 B

    const int tid = threadIdx.x;
    const int wave = tid >> 6;
    const int lane = tid & 63;
    const int m = lane & 15;
    const int quad = lane >> 4;
    const int row0 = blockIdx.x * 256 + wave * 64;
    const bool live = (row0 < NN);

    // DMA instr j writes rows j*16 + (lane>>2); phys granule lane&3 (16B granules).
    // Phys granule g of row r holds logical granule g ^ (r&3):
    const int rrow = lane >> 2;                     // (row&3) == rrow&3
    const int rc4 = (lane & 3) ^ (rrow & 3);        // logical granule fetched
    const float* rbase = feats + (size_t)(row0 + rrow) * CI + rc4 * 4;

    auto stage_res = [&](int cc, int b) {
#pragma unroll
        for (int j = 0; j < 4; ++j)
            dma16(rbase + (size_t)(j * 16) * CI + cc * 16, &s_res[b][wave][j * 16][0]);
    };

    if (live) { stage_res(0, 0); stage_res(1, 1); }   // lands during conv

    // ---- neighbor table ----
    {
        int grow = blockIdx.x * 256 + tid;
        if (grow < NN) {
            int c = coords[grow];
            int y = c / WW, x = c - y * WW;
#pragma unroll
            for (int t = 0; t < 9; ++t) {
                int dy = t / 3 - 1, dx = t % 3 - 1;
                int ny = y + dy, nx = x + dx;
                int r = -1;
                if (ny >= 0 && ny < HH && nx >= 0 && nx < WW) r = idx_map[ny * WW + nx];
                s_nbr[tid * 9 + t] = r;
            }
        } else {
#pragma unroll
            for (int t = 0; t < 9; ++t) s_nbr[tid * 9 + t] = -1;
        }
    }
    __syncthreads();
    if (!live) return;

    // ---- conv 3x3, 2-deep gather pipeline ----
    f32x4 acc[4][4];
#pragma unroll
    for (int rt = 0; rt < 4; ++rt)
#pragma unroll
        for (int ct = 0; ct < 4; ++ct) acc[rt][ct] = (f32x4){0.f, 0.f, 0.f, 0.f};

    bf16x8 ga[2][4][2];
#pragma unroll
    for (int rt = 0; rt < 4; ++rt) {
        int r = s_nbr[(wave * 64 + rt * 16 + m) * 9 + 0];
        const unsigned short* base = (r >= 0) ? (out1 + (size_t)r * CB) : zrow;
        ga[0][rt][0] = ldfrag(base + quad * 8);
        ga[0][rt][1] = ldfrag(base + quad * 8 + 32);
    }

#pragma unroll
    for (int t = 0; t < 9; ++t) {
        const int cur = t & 1, nxt = cur ^ 1;
        if (t < 8) {
#pragma unroll
            for (int rt = 0; rt < 4; ++rt) {
                int r = s_nbr[(wave * 64 + rt * 16 + m) * 9 + t + 1];
                const unsigned short* base = (r >= 0) ? (out1 + (size_t)r * CB) : zrow;
                ga[nxt][rt][0] = ldfrag(base + quad * 8);
                ga[nxt][rt][1] = ldfrag(base + quad * 8 + 32);
            }
        }
#pragma unroll
        for (int ks = 0; ks < 2; ++ks)
#pragma unroll
            for (int ct = 0; ct < 4; ++ct) {
                bf16x8 wb = ldfrag(w2t + t * CB * CB + (ct * 16 + m) * CB + quad * 8 + ks * 32);
#pragma unroll
                for (int rt = 0; rt < 4; ++rt)
                    acc[rt][ct] = mfma16(wb, ga[cur][rt][ks], acc[rt][ct]);
            }
    }

    // ---- bn2 + relu -> bf16 -> per-rt wave-local transpose -> a3 frags ----
    bf16x8 a3[4][2];
#pragma unroll
    for (int rt = 0; rt < 4; ++rt) {
#pragma unroll
        for (int ct = 0; ct < 4; ++ct) {
            int c0 = ct * 16 + quad * 4;
            float4 sc = *(const float4*)(s2 + c0);
            float4 bi = *(const float4*)(b2 + c0);
            float v0 = acc[rt][ct][0] * sc.x + bi.x;
            float v1 = acc[rt][ct][1] * sc.y + bi.y;
            float v2 = acc[rt][ct][2] * sc.z + bi.z;
            float v3 = acc[rt][ct][3] * sc.w + bi.w;
            u16x4 o;
            o.x = f2bf(v0 > 0.f ? v0 : 0.f);
            o.y = f2bf(v1 > 0.f ? v1 : 0.f);
            o.z = f2bf(v2 > 0.f ? v2 : 0.f);
            o.w = f2bf(v3 > 0.f ? v3 : 0.f);
            *(u16x4*)&s_x[wave][m][c0] = o;
        }
        a3[rt][0] = ldfrag(&s_x[wave][m][quad * 8]);
        a3[rt][1] = ldfrag(&s_x[wave][m][32 + quad * 8]);
    }

    // ---- gemm3: 16 chunks of 16 cols, residual from LDS dbuf ----
#pragma unroll
    for (int cc = 0; cc < 16; ++cc) {
        const int b = cc & 1;
        bf16x8 w3f0 = ldfrag(w3t + (cc * 16 + m) * CB + quad * 8);
        bf16x8 w3f1 = ldfrag(w3t + (cc * 16 + m) * CB + quad * 8 + 32);

        f32x4 acc3[4];
#pragma unroll
        for (int rt = 0; rt < 4; ++rt) acc3[rt] = (f32x4){0.f, 0.f, 0.f, 0.f};
#pragma unroll
        for (int rt = 0; rt < 4; ++rt) acc3[rt] = mfma16(w3f0, a3[rt][0], acc3[rt]);
#pragma unroll
        for (int rt = 0; rt < 4; ++rt) acc3[rt] = mfma16(w3f1, a3[rt][1], acc3[rt]);

        // wait for buf b's DMAs before reading s_res
        if (cc == 0) {
            asm volatile("s_waitcnt vmcnt(0)" ::: "memory");
        } else {
            asm volatile("s_waitcnt vmcnt(8)" ::: "memory");
        }
        FENCE();

        const int c0 = cc * 16 + quad * 4;
        float4 sc = *(const float4*)(s3 + c0);
        float4 bi = *(const float4*)(b3 + c0);
#pragma unroll
        for (int rt = 0; rt < 4; ++rt) {
            int row = rt * 16 + m;
            float4 f = *(const float4*)&s_res[b][wave][row][(quad ^ (m & 3)) * 4];
            float4 v;
            v.x = acc3[rt][0] * sc.x + bi.x + f.x;
            v.y = acc3[rt][1] * sc.y + bi.y + f.y;
            v.z = acc3[rt][2] * sc.z + bi.z + f.z;
            v.w = acc3[rt][3] * sc.w + bi.w + f.w;
            v.x = v.x > 0.f ? v.x : 0.f;
            v.y = v.y > 0.f ? v.y : 0.f;
            v.z = v.z > 0.f ? v.z : 0.f;
            v.w = v.w > 0.f ? v.w : 0.f;
            *(float4*)(out + (size_t)(row0 + row) * CI + c0) = v;
        }
        // WAR: s_res reads landed before restage overwrites buf b
        if (cc < 14) {
            LGKM0();
            stage_res(cc + 2, b);
        }
    }
}

// ---------------- launch ----------------

extern "C" void kernel_launch(void* const* d_in, const int* in_sizes, int n_in,
                              void* d_out, int out_size, void* d_ws, size_t ws_size,
                              hipStream_t stream) {
    const float* feats = (const float*)d_in[0];
    const int* coords = (const int*)d_in[1];
    const float* w1 = (const float*)d_in[2];
    const float* w2 = (const float*)d_in[3];
    const float* w3 = (const float*)d_in[4];
    const float* s1 = (const float*)d_in[5];
    const float* b1 = (const float*)d_in[6];
    const float* s2 = (const float*)d_in[7];
    const float* b2 = (const float*)d_in[8];
    const float* s3 = (const float*)d_in[9];
    const float* b3 = (const float*)d_in[10];
    float* out = (float*)d_out;

    char* ws = (char*)d_ws;
    int* idx_map        = (int*)(ws + 0);                       // 2,359,296
    unsigned short* w1t = (unsigned short*)(ws + 2359296);      // 32,768
    unsigned short* w2t = (unsigned short*)(ws + 2392064);      // 73,728
    unsigned short* w3t = (unsigned short*)(ws + 2465792);      // 32,768
    unsigned short* out1= (unsigned short*)(ws + 2498560);      // 25,600,000
    unsigned short* zrow= (unsigned short*)(ws + 53698560);     // 128 zero bytes
    // total: 53,698,688 bytes

    hipMemsetAsync(idx_map, 0xFF, (size_t)HH * WW * 4, stream);
    hipMemsetAsync(zrow, 0x00, 128, stream);
    k_scatter<<<(NN + 255) / 256, 256, 0, stream>>>(coords, idx_map);
    k_prepw<<<64, 256, 0, stream>>>(w1, w2, w3, w1t, w2t, w3t);
    k_gemm1<<<(NN + 127) / 128, 256, 0, stream>>>(feats, w1t, s1, b1, out1);
    k_conv3<<<(NN + 255) / 256, 256, 0, stream>>>(out1, w2t, w3t, coords, idx_map,
                                                  s2, b2, s3, b3, zrow, feats, out);
}